// Round 2
// baseline (1061.826 us; speedup 1.0000x reference)
//
#include <hip/hip_runtime.h>

typedef unsigned short u16;
typedef unsigned int   u32;
typedef __attribute__((ext_vector_type(8))) __bf16 bf16x8;
typedef __attribute__((ext_vector_type(4))) float  f32x4;

// ---------------- problem constants ----------------
#define TT   4096      // tokens
#define HD   1024      // hidden
#define NE   8         // experts
#define DF   4096      // ffn dim
#define NROW 12288     // 2*TT routed rows + TT residual rows

// ---------------- workspace layout (bytes, all 256-aligned) ----------------
#define OFF_XCAT   ((size_t)0)                         // [TT][3072] bf16  = 25165824
#define OFF_WBCAT  (OFF_XCAT  + 25165824)              // [HD][3072] bf16  = 6291456
#define OFF_W1T    (OFF_WBCAT + 6291456)               // [9][DF][HD] bf16 = 75497472
#define OFF_W2T    (OFF_W1T   + 75497472)              // [9][HD][DF] bf16 = 75497472
#define OFF_B1S    (OFF_W2T   + 75497472)              // [9][DF] f32      = 147456
#define OFF_B2S    (OFF_B1S   + 147456)                // [9][HD] f32      = 36864
#define OFF_H32    (OFF_B2S   + 36864)                 // [TT][HD] f32     = 16777216
#define OFF_HBF    (OFF_H32   + 16777216)              // [TT][HD] bf16    = 8388608
#define OFF_HPERM  (OFF_HBF   + 8388608)               // [NROW][HD] bf16  = 25165824
#define OFF_MID    (OFF_HPERM + 25165824)              // [NROW][DF] bf16  = 100663296
#define OFF_EOUT   (OFF_MID   + 100663296)             // [NROW][HD] f32   = 50331648
#define OFF_TOKA   (OFF_EOUT  + 50331648)              // [TT] int4        = 65536
#define OFF_TOKB   (OFF_TOKA  + 65536)                 // [TT] float4      = 65536
#define OFF_META   (OFF_TOKB  + 65536)                 // cnt[16] off[16] me[8] ce[8]

__device__ __forceinline__ u16 f2bf(float f) {
  u32 u = __builtin_bit_cast(u32, f);
  u += 0x7fffu + ((u >> 16) & 1u);          // RTNE
  return (u16)(u >> 16);
}
__device__ __forceinline__ float bf2f(u16 h) {
  u32 u = ((u32)h) << 16;
  return __builtin_bit_cast(float, u);
}
__device__ __forceinline__ u32 pack2(u16 a, u16 b) {
  return (u32)a | ((u32)b << 16);
}

// ---------------- conversion kernels ----------------

// x [TT][HD] f32 -> xcat [TT][3072] bf16 = [hi | hi | lo]; 8 elems/thread, uint4 stores
__global__ __launch_bounds__(256) void xcat_kernel(const float* __restrict__ x,
                                                   u16* __restrict__ out) {
  int idx8 = (blockIdx.x * 256 + threadIdx.x) * 8;   // 0 .. 4M-1 step 8
  int t = idx8 >> 10, k = idx8 & 1023;
  float v[8];
  *(float4*)&v[0] = *(const float4*)(x + idx8);
  *(float4*)&v[4] = *(const float4*)(x + idx8 + 4);
  u16 hi[8], lo[8];
  #pragma unroll
  for (int j = 0; j < 8; ++j) {
    hi[j] = f2bf(v[j]);
    lo[j] = f2bf(v[j] - bf2f(hi[j]));
  }
  uint4 HI = make_uint4(pack2(hi[0], hi[1]), pack2(hi[2], hi[3]),
                        pack2(hi[4], hi[5]), pack2(hi[6], hi[7]));
  uint4 LO = make_uint4(pack2(lo[0], lo[1]), pack2(lo[2], lo[3]),
                        pack2(lo[4], lo[5]), pack2(lo[6], lo[7]));
  size_t rb = (size_t)t * 3072 + k;
  *(uint4*)&out[rb]        = HI;
  *(uint4*)&out[rb + 1024] = HI;
  *(uint4*)&out[rb + 2048] = LO;
}

// Wb [HD][HD] f32 -> WbcatT [HD(n)][3072] bf16 rows = [hi(W^T) | lo(W^T) | hi(W^T)]
__global__ __launch_bounds__(256) void wbcat_kernel(const float* __restrict__ Wb,
                                                    u16* __restrict__ out) {
  __shared__ float tile[64][65];
  int c0 = blockIdx.x * 64, r0 = blockIdx.y * 64;
  int tx = threadIdx.x & 63, ty = threadIdx.x >> 6;
  #pragma unroll
  for (int j = 0; j < 16; ++j) {
    int r = ty + j * 4;
    tile[r][tx] = Wb[(size_t)(r0 + r) * HD + c0 + tx];
  }
  __syncthreads();
  // store: lane q=r-octet, cc col; uint4 = 8 bf16 contiguous in r
  int lane = threadIdx.x & 63, wid = threadIdx.x >> 6;
  int q = lane & 7, cc = lane >> 3;
  #pragma unroll
  for (int h = 0; h < 2; ++h) {
    int c = h * 32 + wid * 8 + cc;
    int rb = q * 8;
    u16 hi[8], lo[8];
    #pragma unroll
    for (int j = 0; j < 8; ++j) {
      float w = tile[rb + j][c];                // Wb[r0+rb+j][c0+c]
      hi[j] = f2bf(w);
      lo[j] = f2bf(w - bf2f(hi[j]));
    }
    uint4 HI = make_uint4(pack2(hi[0], hi[1]), pack2(hi[2], hi[3]),
                          pack2(hi[4], hi[5]), pack2(hi[6], hi[7]));
    uint4 LO = make_uint4(pack2(lo[0], lo[1]), pack2(lo[2], lo[3]),
                          pack2(lo[4], lo[5]), pack2(lo[6], lo[7]));
    size_t ob = (size_t)(c0 + c) * 3072 + r0 + rb;
    *(uint4*)&out[ob]        = HI;
    *(uint4*)&out[ob + 1024] = LO;
    *(uint4*)&out[ob + 2048] = HI;
  }
}

// generic transpose+convert: in f32 [R][C] (expert z<8: Wmain+z*R*C, z==8: Wres)
// -> out bf16 [C][R] at out+z*R*C ; uint4 (8xbf16) stores
__global__ __launch_bounds__(256) void transpose_cvt(const float* __restrict__ Wmain,
                                                     const float* __restrict__ Wres,
                                                     u16* __restrict__ out,
                                                     int R, int C) {
  __shared__ float tile[64][65];
  int e = blockIdx.z;
  const float* in = (e < 8) ? (Wmain + (size_t)e * R * C) : Wres;
  u16* o = out + (size_t)e * R * C;
  int c0 = blockIdx.x * 64, r0 = blockIdx.y * 64;
  int tx = threadIdx.x & 63, ty = threadIdx.x >> 6;
  #pragma unroll
  for (int j = 0; j < 16; ++j) {
    int r = ty + j * 4;
    tile[r][tx] = in[(size_t)(r0 + r) * C + c0 + tx];
  }
  __syncthreads();
  int lane = threadIdx.x & 63, wid = threadIdx.x >> 6;
  int q = lane & 7, cc = lane >> 3;
  #pragma unroll
  for (int h = 0; h < 2; ++h) {
    int c = h * 32 + wid * 8 + cc;
    int rb = q * 8;
    u16 b[8];
    #pragma unroll
    for (int j = 0; j < 8; ++j) b[j] = f2bf(tile[rb + j][c]);
    uint4 P = make_uint4(pack2(b[0], b[1]), pack2(b[2], b[3]),
                         pack2(b[4], b[5]), pack2(b[6], b[7]));
    *(uint4*)&o[(size_t)(c0 + c) * R + r0 + rb] = P;
  }
}

// stack biases + zero meta
__global__ __launch_bounds__(256) void prep_kernel(const float* __restrict__ b1,
                                                   const float* __restrict__ br1,
                                                   const float* __restrict__ b2,
                                                   const float* __restrict__ br2,
                                                   float* __restrict__ b1s,
                                                   float* __restrict__ b2s,
                                                   int* __restrict__ cnt,
                                                   int* __restrict__ off,
                                                   float* __restrict__ me,
                                                   float* __restrict__ ce) {
  int idx = blockIdx.x * 256 + threadIdx.x;
  if (idx < 36864) {
    b1s[idx] = (idx < 32768) ? b1[idx] : br1[idx - 32768];
  } else if (idx < 46080) {
    int j = idx - 36864;
    b2s[j] = (j < 8192) ? b2[j] : br2[j - 8192];
  } else if (idx < 46144) {
    int j = idx - 46080;
    if (j < 16) cnt[j] = 0;
    else if (j < 32) off[j - 16] = 0;
    else if (j < 40) me[j - 32] = 0.f;
    else if (j < 48) ce[j - 40] = 0.f;
  }
}

// ---------------- the GEMM (m97 structure + XOR LDS swizzle) ----------------
// C[M,N] = A[M,K] @ BT[N,K]^T ; grouped rows [off[z], off[z+1]) if off != nullptr.
// SWAP=1: blockIdx.x = row-tile (fast), blockIdx.y = col-tile  -> weight-tile-major
// LDS layout: 8-row slabs of 1024B; granule (r,c8) at slab + (r*8 + (c8^r))*16B.
template <int RELU, int OUTF32, int OUTBF16, int SWAP>
__global__ __launch_bounds__(256) void gemm_bt(const u16* __restrict__ A,
                                               const u16* __restrict__ BT,
                                               const float* __restrict__ bias,
                                               float* __restrict__ Cf,
                                               u16* __restrict__ Cb,
                                               const int* __restrict__ off,
                                               int M, int K, int N) {
  __shared__ u16 As[128 * 64];
  __shared__ u16 Bs[128 * 64];
  const int z = blockIdx.z;
  const int bx = SWAP ? blockIdx.y : blockIdx.x;   // col (N) tile
  const int by = SWAP ? blockIdx.x : blockIdx.y;   // row (M) tile
  int base, cntr;
  if (off) { base = off[z]; cntr = off[z + 1] - base; }
  else     { base = 0;      cntr = M; }
  if (by * 128 >= cntr) return;

  const int tid = threadIdx.x, lane = tid & 63, wid = tid >> 6;
  const int wm = wid & 1, wn = wid >> 1;
  const u16* Bz = BT + (size_t)z * N * K;
  // staging: lane -> (row-in-slab r8, XOR-swizzled chunk c8)
  const int r8 = lane >> 3;
  const int c8 = (lane & 7) ^ r8;
  const int colb = c8 * 8;           // u16 col within 64-wide k-slab

  f32x4 acc[4][4] = {};

  const int kiters = K >> 6;
  for (int kt = 0; kt < kiters; ++kt) {
    #pragma unroll
    for (int i = 0; i < 4; ++i) {
      int rt = wid * 32 + i * 8 + r8;
      int lr = by * 128 + rt;
      lr = lr < cntr ? lr : cntr - 1;                       // clamp ragged tail
      const u16* ga = A + (size_t)(base + lr) * K + kt * 64 + colb;
      __builtin_amdgcn_global_load_lds(
          (const __attribute__((address_space(1))) void*)ga,
          (__attribute__((address_space(3))) void*)&As[(wid * 32 + i * 8) * 64],
          16, 0, 0);
      int nn = bx * 128 + rt;
      const u16* gb = Bz + (size_t)nn * K + kt * 64 + colb;
      __builtin_amdgcn_global_load_lds(
          (const __attribute__((address_space(1))) void*)gb,
          (__attribute__((address_space(3))) void*)&Bs[(wid * 32 + i * 8) * 64],
          16, 0, 0);
    }
    __syncthreads();
    {
      const int rsel = lane & 15, quad = lane >> 4;
      const int rr = rsel & 7, rhi = rsel >> 3;
      #pragma unroll
      for (int kk = 0; kk < 2; ++kk) {
        const int sc = (kk * 4 + quad) ^ rr;     // swizzled chunk
        bf16x8 af[4], bfr[4];
        #pragma unroll
        for (int mt = 0; mt < 4; ++mt) {
          int slab = wm * 8 + mt * 2 + rhi;
          af[mt] = *(const bf16x8*)&As[slab * 512 + rr * 64 + sc * 8];
        }
        #pragma unroll
        for (int nt = 0; nt < 4; ++nt) {
          int slab = wn * 8 + nt * 2 + rhi;
          bfr[nt] = *(const bf16x8*)&Bs[slab * 512 + rr * 64 + sc * 8];
        }
        #pragma unroll
        for (int mt = 0; mt < 4; ++mt)
          #pragma unroll
          for (int nt = 0; nt < 4; ++nt)
            acc[mt][nt] = __builtin_amdgcn_mfma_f32_16x16x32_bf16(
                af[mt], bfr[nt], acc[mt][nt], 0, 0, 0);
      }
    }
    __syncthreads();
  }

  // epilogue: C/D layout col=lane&15, row=(lane>>4)*4+i  [verified m89/m91]
  const int rq = (lane >> 4) * 4, cq = lane & 15;
  #pragma unroll
  for (int nt = 0; nt < 4; ++nt) {
    int gc = bx * 128 + wn * 64 + nt * 16 + cq;
    float bv = bias ? bias[(size_t)z * N + gc] : 0.f;
    #pragma unroll
    for (int mt = 0; mt < 4; ++mt) {
      #pragma unroll
      for (int i = 0; i < 4; ++i) {
        int rt = wm * 64 + mt * 16 + rq + i;
        int lr = by * 128 + rt;
        if (lr < cntr) {
          float v = acc[mt][nt][i] + bv;
          if (RELU) v = fmaxf(v, 0.f);
          size_t idx = (size_t)(base + lr) * N + gc;
          if (OUTF32)  Cf[idx] = v;
          if (OUTBF16) Cb[idx] = f2bf(v);
        }
      }
    }
  }
}

// ---------------- gating: softmax, top-2, coef, me/ce, ranks ----------------
__global__ __launch_bounds__(256) void gating_kernel(const float* __restrict__ h32,
                                                     const float* __restrict__ Wg,
                                                     const float* __restrict__ Wc,
                                                     const float* __restrict__ bc,
                                                     int4* __restrict__ tokA,
                                                     float4* __restrict__ tokB,
                                                     float* __restrict__ me,
                                                     float* __restrict__ ce,
                                                     int* __restrict__ cnt) {
  __shared__ float lme[8];
  __shared__ float lce[8];
  int tid = threadIdx.x, lane = tid & 63, wid = tid >> 6;
  if (tid < 8) { lme[tid] = 0.f; lce[tid] = 0.f; }
  __syncthreads();

  int t = blockIdx.x * 4 + wid;
  const float* hr = h32 + (size_t)t * HD;
  float g[8] = {0, 0, 0, 0, 0, 0, 0, 0};
  float c0 = 0.f, c1 = 0.f;
  for (int cc = 0; cc < 4; ++cc) {
    int k0 = cc * 256 + lane * 4;
    float hv[4];
    *(float4*)hv = *(const float4*)(hr + k0);
    #pragma unroll
    for (int i = 0; i < 4; ++i) {
      float hx = hv[i];
      const float4* wg = (const float4*)(Wg + (size_t)(k0 + i) * 8);
      float4 w0 = wg[0], w1 = wg[1];
      g[0] += hx * w0.x; g[1] += hx * w0.y; g[2] += hx * w0.z; g[3] += hx * w0.w;
      g[4] += hx * w1.x; g[5] += hx * w1.y; g[6] += hx * w1.z; g[7] += hx * w1.w;
      float2 wc = *(const float2*)(Wc + (size_t)(k0 + i) * 2);
      c0 += hx * wc.x; c1 += hx * wc.y;
    }
  }
  #pragma unroll
  for (int s = 32; s > 0; s >>= 1) {
    #pragma unroll
    for (int e = 0; e < 8; ++e) g[e] += __shfl_down(g[e], s);
    c0 += __shfl_down(c0, s);
    c1 += __shfl_down(c1, s);
  }
  if (lane == 0) {
    float m = g[0];
    #pragma unroll
    for (int e = 1; e < 8; ++e) m = fmaxf(m, g[e]);
    float ex[8], ssum = 0.f;
    #pragma unroll
    for (int e = 0; e < 8; ++e) { ex[e] = expf(g[e] - m); ssum += ex[e]; }
    float inv = 1.f / ssum;
    float ge[8];
    #pragma unroll
    for (int e = 0; e < 8; ++e) ge[e] = ex[e] * inv;
    float v0 = -1.f, v1 = -1.f; int i0 = 0, i1 = 0;
    #pragma unroll
    for (int e = 0; e < 8; ++e) {
      float v = ge[e];
      if (v > v0)      { v1 = v0; i1 = i0; v0 = v; i0 = e; }
      else if (v > v1) { v1 = v; i1 = e; }
    }
    float wsum = v0 + v1 + 1e-9f;
    float w0 = v0 / wsum, w1 = v1 / wsum;
    float ca = c0 + bc[0], cb = c1 + bc[1];
    float mm = fmaxf(ca, cb);
    float e0 = expf(ca - mm), e1 = expf(cb - mm);
    float cinv = 1.f / (e0 + e1);
    int r0 = atomicAdd(&cnt[i0], 1);
    int r1 = atomicAdd(&cnt[i1], 1);
    tokA[t] = make_int4(i0, i1, r0, r1);
    tokB[t] = make_float4(w0, w1, e0 * cinv, e1 * cinv);
    #pragma unroll
    for (int e = 0; e < 8; ++e) atomicAdd(&lme[e], ge[e]);
    atomicAdd(&lce[i0], 1.f);
  }
  __syncthreads();
  if (tid < 8) { atomicAdd(&me[tid], lme[tid]); atomicAdd(&ce[tid], lce[tid]); }
}

// ---------------- scan offsets + l_aux ----------------
__global__ void scan_kernel(const int* __restrict__ cnt, int* __restrict__ off,
                            const float* __restrict__ me, const float* __restrict__ ce,
                            float* __restrict__ laux) {
  if (threadIdx.x == 0) {
    int o = 0;
    for (int e = 0; e < 8; ++e) { off[e] = o; o += cnt[e]; }
    off[8] = o;            // == 8192
    off[9] = o + TT;       // == 12288
    float s = 0.f;
    for (int e = 0; e < 8; ++e) s += me[e] * ce[e];
    laux[0] = s * 8.f / ((float)TT * (float)TT);
  }
}

// ---------------- scatter h rows into permuted layout ----------------
__global__ __launch_bounds__(256) void scatter_kernel(const u16* __restrict__ hbf,
                                                      u16* __restrict__ hperm,
                                                      const int4* __restrict__ tokA,
                                                      const int* __restrict__ off) {
  int t = blockIdx.x, tid = threadIdx.x;
  int4 a = tokA[t];
  size_t p0 = (size_t)(off[a.x] + a.z) * HD;
  size_t p1 = (size_t)(off[a.y] + a.w) * HD;
  size_t pr = (size_t)(8192 + t) * HD;
  uint2 v = ((const uint2*)(hbf + (size_t)t * HD))[tid];
  ((uint2*)(hperm + p0))[tid] = v;
  ((uint2*)(hperm + p1))[tid] = v;
  ((uint2*)(hperm + pr))[tid] = v;
}

// ---------------- combine + classification head ----------------
__global__ __launch_bounds__(256) void combine_head(const float* __restrict__ eout,
                                                    const int4* __restrict__ tokA,
                                                    const float4* __restrict__ tokB,
                                                    const int* __restrict__ off,
                                                    const float* __restrict__ Wh,
                                                    const float* __restrict__ bh,
                                                    float* __restrict__ logits) {
  int tid = threadIdx.x, lane = tid & 63, wid = tid >> 6;
  int t = blockIdx.x * 4 + wid;
  int4 a = tokA[t];
  float4 b = tokB[t];
  const float* p0 = eout + (size_t)(off[a.x] + a.z) * HD;
  const float* p1 = eout + (size_t)(off[a.y] + a.w) * HD;
  const float* pr = eout + (size_t)(8192 + t) * HD;
  float acc[10] = {};
  for (int cc = 0; cc < 4; ++cc) {
    int k0 = cc * 256 + lane * 4;
    float v0[4], v1[4], vr[4];
    *(float4*)v0 = *(const float4*)(p0 + k0);
    *(float4*)v1 = *(const float4*)(p1 + k0);
    *(float4*)vr = *(const float4*)(pr + k0);
    #pragma unroll
    for (int i = 0; i < 4; ++i) {
      float outv = b.z * (b.x * v0[i] + b.y * v1[i]) + b.w * vr[i];
      const float* wr = Wh + (size_t)(k0 + i) * 10;
      #pragma unroll
      for (int j = 0; j < 10; ++j) acc[j] += outv * wr[j];
    }
  }
  #pragma unroll
  for (int s = 32; s > 0; s >>= 1) {
    #pragma unroll
    for (int j = 0; j < 10; ++j) acc[j] += __shfl_down(acc[j], s);
  }
  if (lane == 0) {
    #pragma unroll
    for (int j = 0; j < 10; ++j) logits[(size_t)t * 10 + j] = acc[j] + bh[j];
  }
}

// ---------------- launch ----------------
extern "C" void kernel_launch(void* const* d_in, const int* in_sizes, int n_in,
                              void* d_out, int out_size, void* d_ws, size_t ws_size,
                              hipStream_t stream) {
  const float* x   = (const float*)d_in[0];
  const float* Wb  = (const float*)d_in[1];
  const float* bb  = (const float*)d_in[2];
  const float* Wg  = (const float*)d_in[3];
  const float* W1  = (const float*)d_in[4];
  const float* b1  = (const float*)d_in[5];
  const float* W2  = (const float*)d_in[6];
  const float* b2  = (const float*)d_in[7];
  const float* Wr1 = (const float*)d_in[8];
  const float* br1 = (const float*)d_in[9];
  const float* Wr2 = (const float*)d_in[10];
  const float* br2 = (const float*)d_in[11];
  const float* Wc  = (const float*)d_in[12];
  const float* bc  = (const float*)d_in[13];
  const float* Wh  = (const float*)d_in[14];
  const float* bh  = (const float*)d_in[15];
  float* out = (float*)d_out;

  char* w = (char*)d_ws;
  u16*    xcat  = (u16*)(w + OFF_XCAT);
  u16*    wbcat = (u16*)(w + OFF_WBCAT);
  u16*    w1t   = (u16*)(w + OFF_W1T);
  u16*    w2t   = (u16*)(w + OFF_W2T);
  float*  b1s   = (float*)(w + OFF_B1S);
  float*  b2s   = (float*)(w + OFF_B2S);
  float*  h32   = (float*)(w + OFF_H32);
  u16*    hbf   = (u16*)(w + OFF_HBF);
  u16*    hperm = (u16*)(w + OFF_HPERM);
  u16*    mid   = (u16*)(w + OFF_MID);
  float*  eout  = (float*)(w + OFF_EOUT);
  int4*   tokA  = (int4*)(w + OFF_TOKA);
  float4* tokB  = (float4*)(w + OFF_TOKB);
  int*    cnt   = (int*)(w + OFF_META);
  int*    off   = cnt + 16;
  float*  me    = (float*)(off + 16);
  float*  ce    = me + 8;

  // conversions (independent)
  xcat_kernel<<<dim3(2048), dim3(256), 0, stream>>>(x, xcat);
  wbcat_kernel<<<dim3(16, 16), dim3(256), 0, stream>>>(Wb, wbcat);
  transpose_cvt<<<dim3(64, 16, 9), dim3(256), 0, stream>>>(W1, Wr1, w1t, 1024, 4096);
  transpose_cvt<<<dim3(16, 64, 9), dim3(256), 0, stream>>>(W2, Wr2, w2t, 4096, 1024);
  prep_kernel<<<dim3(181), dim3(256), 0, stream>>>(b1, br1, b2, br2, b1s, b2s, cnt, off, me, ce);

  // G1: h = relu(x@Wb + bb), split-bf16 (K=3072) for ~fp32 gate fidelity
  gemm_bt<1, 1, 1, 0><<<dim3(8, 32, 1), dim3(256), 0, stream>>>(
      xcat, wbcat, bb, h32, hbf, (const int*)nullptr, 4096, 3072, 1024);

  gating_kernel<<<dim3(1024), dim3(256), 0, stream>>>(h32, Wg, Wc, bc, tokA, tokB, me, ce, cnt);
  scan_kernel<<<dim3(1), dim3(64), 0, stream>>>(cnt, off, me, ce, out + 40960);
  scatter_kernel<<<dim3(4096), dim3(256), 0, stream>>>(hbf, hperm, tokA, off);

  // G2: mid = relu(hperm @ W1[e] + b1[e]) grouped over 9 "experts" (8 MoE + residual)
  gemm_bt<1, 0, 1, 0><<<dim3(32, 32, 9), dim3(256), 0, stream>>>(
      hperm, w1t, b1s, (float*)nullptr, mid, off, 0, 1024, 4096);
  // G3: eout = mid @ W2[e] + b2[e]  -- SWAP: weight-tile-major dispatch for L2 reuse
  gemm_bt<0, 1, 0, 1><<<dim3(32, 8, 9), dim3(256), 0, stream>>>(
      mid, w2t, b2s, eout, (u16*)nullptr, off, 0, 4096, 1024);

  combine_head<<<dim3(1024), dim3(256), 0, stream>>>(eout, tokA, tokB, off, Wh, bh, out);
}

// Round 4
// 913.485 us; speedup vs baseline: 1.1624x; 1.1624x over previous
//
#include <hip/hip_runtime.h>

typedef unsigned short u16;
typedef unsigned int   u32;
typedef __attribute__((ext_vector_type(8))) __bf16 bf16x8;
typedef __attribute__((ext_vector_type(4))) float  f32x4;

// ---------------- problem constants ----------------
#define TT   4096      // tokens
#define HD   1024      // hidden
#define NE   8         // experts
#define DF   4096      // ffn dim
#define NROW 12288     // 2*TT routed rows + TT residual rows

// ---------------- workspace layout (bytes, all 256-aligned) ----------------
#define OFF_XCAT   ((size_t)0)                         // [TT][3072] bf16  = 25165824
#define OFF_WBCAT  (OFF_XCAT  + 25165824)              // [HD][3072] bf16  = 6291456
#define OFF_W1T    (OFF_WBCAT + 6291456)               // [9][DF][HD] bf16 = 75497472
#define OFF_W2T    (OFF_W1T   + 75497472)              // [9][HD][DF] bf16 = 75497472
#define OFF_B1S    (OFF_W2T   + 75497472)              // [9][DF] f32      = 147456
#define OFF_B2S    (OFF_B1S   + 147456)                // [9][HD] f32      = 36864
#define OFF_H32    (OFF_B2S   + 36864)                 // [TT][HD] f32     = 16777216
#define OFF_HBF    (OFF_H32   + 16777216)              // [TT][HD] bf16    = 8388608
#define OFF_HPERM  (OFF_HBF   + 8388608)               // [NROW][HD] bf16  = 25165824
#define OFF_MID    (OFF_HPERM + 25165824)              // [NROW][DF] bf16  = 100663296
#define OFF_EOUT   (OFF_MID   + 100663296)             // [NROW][HD] f32   = 50331648
#define OFF_TOKA   (OFF_EOUT  + 50331648)              // [TT] int4        = 65536
#define OFF_TOKB   (OFF_TOKA  + 65536)                 // [TT] float4      = 65536
#define OFF_META   (OFF_TOKB  + 65536)                 // cnt[16] off[16] me[8] ce[8]
// Aliased (lifetime-disjoint, stream-ordered):
//   h32b  = OFF_EOUT  (16 MB; used G1..relu_cast, before G3 writes eout)
//   eoutB = OFF_XCAT  (48 MB; overlays xcat+wbcat+w1t[0:18MB], all dead after G2)

__device__ __forceinline__ u16 f2bf(float f) {
  u32 u = __builtin_bit_cast(u32, f);
  u += 0x7fffu + ((u >> 16) & 1u);          // RTNE
  return (u16)(u >> 16);
}
__device__ __forceinline__ float bf2f(u16 h) {
  u32 u = ((u32)h) << 16;
  return __builtin_bit_cast(float, u);
}
__device__ __forceinline__ u32 pack2(u16 a, u16 b) {
  return (u32)a | ((u32)b << 16);
}

// ---------------- conversion kernels ----------------

// x [TT][HD] f32 -> xcat [TT][3072] bf16 = [hi | hi | lo]; 8 elems/thread, uint4 stores
__global__ __launch_bounds__(256) void xcat_kernel(const float* __restrict__ x,
                                                   u16* __restrict__ out) {
  int idx8 = (blockIdx.x * 256 + threadIdx.x) * 8;   // 0 .. 4M-1 step 8
  int t = idx8 >> 10, k = idx8 & 1023;
  float v[8];
  *(float4*)&v[0] = *(const float4*)(x + idx8);
  *(float4*)&v[4] = *(const float4*)(x + idx8 + 4);
  u16 hi[8], lo[8];
  #pragma unroll
  for (int j = 0; j < 8; ++j) {
    hi[j] = f2bf(v[j]);
    lo[j] = f2bf(v[j] - bf2f(hi[j]));
  }
  uint4 HI = make_uint4(pack2(hi[0], hi[1]), pack2(hi[2], hi[3]),
                        pack2(hi[4], hi[5]), pack2(hi[6], hi[7]));
  uint4 LO = make_uint4(pack2(lo[0], lo[1]), pack2(lo[2], lo[3]),
                        pack2(lo[4], lo[5]), pack2(lo[6], lo[7]));
  size_t rb = (size_t)t * 3072 + k;
  *(uint4*)&out[rb]        = HI;
  *(uint4*)&out[rb + 1024] = HI;
  *(uint4*)&out[rb + 2048] = LO;
}

// Wb [HD][HD] f32 -> WbcatT [HD(n)][3072] bf16 rows = [hi(W^T) | lo(W^T) | hi(W^T)]
__global__ __launch_bounds__(256) void wbcat_kernel(const float* __restrict__ Wb,
                                                    u16* __restrict__ out) {
  __shared__ float tile[64][65];
  int c0 = blockIdx.x * 64, r0 = blockIdx.y * 64;
  int tx = threadIdx.x & 63, ty = threadIdx.x >> 6;
  #pragma unroll
  for (int j = 0; j < 16; ++j) {
    int r = ty + j * 4;
    tile[r][tx] = Wb[(size_t)(r0 + r) * HD + c0 + tx];
  }
  __syncthreads();
  int lane = threadIdx.x & 63, wid = threadIdx.x >> 6;
  int q = lane & 7, cc = lane >> 3;
  #pragma unroll
  for (int h = 0; h < 2; ++h) {
    int c = h * 32 + wid * 8 + cc;
    int rb = q * 8;
    u16 hi[8], lo[8];
    #pragma unroll
    for (int j = 0; j < 8; ++j) {
      float w = tile[rb + j][c];                // Wb[r0+rb+j][c0+c]
      hi[j] = f2bf(w);
      lo[j] = f2bf(w - bf2f(hi[j]));
    }
    uint4 HI = make_uint4(pack2(hi[0], hi[1]), pack2(hi[2], hi[3]),
                          pack2(hi[4], hi[5]), pack2(hi[6], hi[7]));
    uint4 LO = make_uint4(pack2(lo[0], lo[1]), pack2(lo[2], lo[3]),
                          pack2(lo[4], lo[5]), pack2(lo[6], lo[7]));
    size_t ob = (size_t)(c0 + c) * 3072 + r0 + rb;
    *(uint4*)&out[ob]        = HI;
    *(uint4*)&out[ob + 1024] = LO;
    *(uint4*)&out[ob + 2048] = HI;
  }
}

// generic transpose+convert: in f32 [R][C] (expert z<8: Wmain+z*R*C, z==8: Wres)
// -> out bf16 [C][R] at out+z*R*C ; uint4 (8xbf16) stores
__global__ __launch_bounds__(256) void transpose_cvt(const float* __restrict__ Wmain,
                                                     const float* __restrict__ Wres,
                                                     u16* __restrict__ out,
                                                     int R, int C) {
  __shared__ float tile[64][65];
  int e = blockIdx.z;
  const float* in = (e < 8) ? (Wmain + (size_t)e * R * C) : Wres;
  u16* o = out + (size_t)e * R * C;
  int c0 = blockIdx.x * 64, r0 = blockIdx.y * 64;
  int tx = threadIdx.x & 63, ty = threadIdx.x >> 6;
  #pragma unroll
  for (int j = 0; j < 16; ++j) {
    int r = ty + j * 4;
    tile[r][tx] = in[(size_t)(r0 + r) * C + c0 + tx];
  }
  __syncthreads();
  int lane = threadIdx.x & 63, wid = threadIdx.x >> 6;
  int q = lane & 7, cc = lane >> 3;
  #pragma unroll
  for (int h = 0; h < 2; ++h) {
    int c = h * 32 + wid * 8 + cc;
    int rb = q * 8;
    u16 b[8];
    #pragma unroll
    for (int j = 0; j < 8; ++j) b[j] = f2bf(tile[rb + j][c]);
    uint4 P = make_uint4(pack2(b[0], b[1]), pack2(b[2], b[3]),
                         pack2(b[4], b[5]), pack2(b[6], b[7]));
    *(uint4*)&o[(size_t)(c0 + c) * R + r0 + rb] = P;
  }
}

// stack biases + zero meta
__global__ __launch_bounds__(256) void prep_kernel(const float* __restrict__ b1,
                                                   const float* __restrict__ br1,
                                                   const float* __restrict__ b2,
                                                   const float* __restrict__ br2,
                                                   float* __restrict__ b1s,
                                                   float* __restrict__ b2s,
                                                   int* __restrict__ cnt,
                                                   int* __restrict__ off,
                                                   float* __restrict__ me,
                                                   float* __restrict__ ce) {
  int idx = blockIdx.x * 256 + threadIdx.x;
  if (idx < 36864) {
    b1s[idx] = (idx < 32768) ? b1[idx] : br1[idx - 32768];
  } else if (idx < 46080) {
    int j = idx - 36864;
    b2s[j] = (j < 8192) ? b2[j] : br2[j - 8192];
  } else if (idx < 46144) {
    int j = idx - 46080;
    if (j < 16) cnt[j] = 0;
    else if (j < 32) off[j - 16] = 0;
    else if (j < 40) me[j - 32] = 0.f;
    else if (j < 48) ce[j - 40] = 0.f;
  }
}

// ---------------- the GEMM (m97 structure + XOR LDS swizzle + split-K partials) ----
// C[M,N] = A[M,K] @ BT[N,K]^T ; grouped rows [off[e], off[e+1]) if off != nullptr.
// KSPLIT=2: blockIdx.z = expert*2 + kchunk; kchunk0 -> Cf (with bias), kchunk1 -> Cf1.
// Plain stores, each address written exactly once per launch -> bitwise deterministic.
// LDS layout: 8-row slabs of 1024B; granule (r,c8) at slab + (r*8 + (c8^r))*16B.
template <int RELU, int OUTF32, int OUTBF16, int KSPLIT>
__global__ __launch_bounds__(256) void gemm_bt(const u16* __restrict__ A,
                                               const u16* __restrict__ BT,
                                               const float* __restrict__ bias,
                                               float* __restrict__ Cf,
                                               float* __restrict__ Cf1,
                                               u16* __restrict__ Cb,
                                               const int* __restrict__ off,
                                               int M, int K, int N) {
  __shared__ u16 As[128 * 64];
  __shared__ u16 Bs[128 * 64];
  const int zz = blockIdx.z;
  const int expert = (KSPLIT > 1) ? (zz / KSPLIT) : zz;
  const int kchunk = (KSPLIT > 1) ? (zz % KSPLIT) : 0;
  const int bx = blockIdx.x;   // col (N) tile
  const int by = blockIdx.y;   // row (M) tile
  int base, cntr;
  if (off) { base = off[expert]; cntr = off[expert + 1] - base; }
  else     { base = 0;           cntr = M; }
  if (by * 128 >= cntr) return;

  const int tid = threadIdx.x, lane = tid & 63, wid = tid >> 6;
  const int wm = wid & 1, wn = wid >> 1;
  const u16* Bz = BT + (size_t)expert * N * K;
  // staging: lane -> (row-in-slab r8, XOR-swizzled chunk c8)
  const int r8 = lane >> 3;
  const int c8 = (lane & 7) ^ r8;
  const int colb = c8 * 8;           // u16 col within 64-wide k-slab

  f32x4 acc[4][4] = {};

  const int kiters = K >> 6;
  const int kspan = kiters / KSPLIT;
  const int kbeg = kchunk * kspan, kend = kbeg + kspan;
  for (int kt = kbeg; kt < kend; ++kt) {
    #pragma unroll
    for (int i = 0; i < 4; ++i) {
      int rt = wid * 32 + i * 8 + r8;
      int lr = by * 128 + rt;
      lr = lr < cntr ? lr : cntr - 1;                       // clamp ragged tail
      const u16* ga = A + (size_t)(base + lr) * K + kt * 64 + colb;
      __builtin_amdgcn_global_load_lds(
          (const __attribute__((address_space(1))) void*)ga,
          (__attribute__((address_space(3))) void*)&As[(wid * 32 + i * 8) * 64],
          16, 0, 0);
      int nn = bx * 128 + rt;
      const u16* gb = Bz + (size_t)nn * K + kt * 64 + colb;
      __builtin_amdgcn_global_load_lds(
          (const __attribute__((address_space(1))) void*)gb,
          (__attribute__((address_space(3))) void*)&Bs[(wid * 32 + i * 8) * 64],
          16, 0, 0);
    }
    __syncthreads();
    {
      const int rsel = lane & 15, quad = lane >> 4;
      const int rr = rsel & 7, rhi = rsel >> 3;
      #pragma unroll
      for (int kk = 0; kk < 2; ++kk) {
        const int sc = (kk * 4 + quad) ^ rr;     // swizzled chunk
        bf16x8 af[4], bfr[4];
        #pragma unroll
        for (int mt = 0; mt < 4; ++mt) {
          int slab = wm * 8 + mt * 2 + rhi;
          af[mt] = *(const bf16x8*)&As[slab * 512 + rr * 64 + sc * 8];
        }
        #pragma unroll
        for (int nt = 0; nt < 4; ++nt) {
          int slab = wn * 8 + nt * 2 + rhi;
          bfr[nt] = *(const bf16x8*)&Bs[slab * 512 + rr * 64 + sc * 8];
        }
        #pragma unroll
        for (int mt = 0; mt < 4; ++mt)
          #pragma unroll
          for (int nt = 0; nt < 4; ++nt)
            acc[mt][nt] = __builtin_amdgcn_mfma_f32_16x16x32_bf16(
                af[mt], bfr[nt], acc[mt][nt], 0, 0, 0);
      }
    }
    __syncthreads();
  }

  // epilogue: C/D layout col=lane&15, row=(lane>>4)*4+i  [verified m89/m91]
  float* __restrict__ dstF = (KSPLIT > 1 && kchunk) ? Cf1 : Cf;
  const int rq = (lane >> 4) * 4, cq = lane & 15;
  #pragma unroll
  for (int nt = 0; nt < 4; ++nt) {
    int gc = bx * 128 + wn * 64 + nt * 16 + cq;
    float bv = (bias && kchunk == 0) ? bias[(size_t)expert * N + gc] : 0.f;
    #pragma unroll
    for (int mt = 0; mt < 4; ++mt) {
      #pragma unroll
      for (int i = 0; i < 4; ++i) {
        int rt = wm * 64 + mt * 16 + rq + i;
        int lr = by * 128 + rt;
        if (lr < cntr) {
          float v = acc[mt][nt][i] + bv;
          if (RELU) v = fmaxf(v, 0.f);
          size_t idx = (size_t)(base + lr) * N + gc;
          if (OUTF32)  dstF[idx] = v;
          if (OUTBF16) Cb[idx] = f2bf(v);
        }
      }
    }
  }
}

// ---------------- sum partials + relu + bf16 cast (after split-K G1) ----------------
__global__ __launch_bounds__(256) void relu_cast(const float* __restrict__ pa,
                                                 const float* __restrict__ pb,
                                                 float* __restrict__ h32,
                                                 u16* __restrict__ hbf) {
  int i8 = (blockIdx.x * 256 + threadIdx.x) * 8;
  float a[8], b[8];
  *(float4*)&a[0] = *(const float4*)(pa + i8);
  *(float4*)&a[4] = *(const float4*)(pa + i8 + 4);
  *(float4*)&b[0] = *(const float4*)(pb + i8);
  *(float4*)&b[4] = *(const float4*)(pb + i8 + 4);
  u16 p[8];
  float v[8];
  #pragma unroll
  for (int j = 0; j < 8; ++j) {
    v[j] = fmaxf(a[j] + b[j], 0.f);
    p[j] = f2bf(v[j]);
  }
  *(float4*)(h32 + i8)     = *(float4*)&v[0];
  *(float4*)(h32 + i8 + 4) = *(float4*)&v[4];
  uint4 P = make_uint4(pack2(p[0], p[1]), pack2(p[2], p[3]),
                       pack2(p[4], p[5]), pack2(p[6], p[7]));
  *(uint4*)&hbf[i8] = P;
}

// ---------------- gating: softmax, top-2, coef, me/ce, ranks ----------------
__global__ __launch_bounds__(256) void gating_kernel(const float* __restrict__ h32,
                                                     const float* __restrict__ Wg,
                                                     const float* __restrict__ Wc,
                                                     const float* __restrict__ bc,
                                                     int4* __restrict__ tokA,
                                                     float4* __restrict__ tokB,
                                                     float* __restrict__ me,
                                                     float* __restrict__ ce,
                                                     int* __restrict__ cnt) {
  __shared__ float lme[8];
  __shared__ float lce[8];
  int tid = threadIdx.x, lane = tid & 63, wid = tid >> 6;
  if (tid < 8) { lme[tid] = 0.f; lce[tid] = 0.f; }
  __syncthreads();

  int t = blockIdx.x * 4 + wid;
  const float* hr = h32 + (size_t)t * HD;
  float g[8] = {0, 0, 0, 0, 0, 0, 0, 0};
  float c0 = 0.f, c1 = 0.f;
  for (int cc = 0; cc < 4; ++cc) {
    int k0 = cc * 256 + lane * 4;
    float hv[4];
    *(float4*)hv = *(const float4*)(hr + k0);
    #pragma unroll
    for (int i = 0; i < 4; ++i) {
      float hx = hv[i];
      const float4* wg = (const float4*)(Wg + (size_t)(k0 + i) * 8);
      float4 w0 = wg[0], w1 = wg[1];
      g[0] += hx * w0.x; g[1] += hx * w0.y; g[2] += hx * w0.z; g[3] += hx * w0.w;
      g[4] += hx * w1.x; g[5] += hx * w1.y; g[6] += hx * w1.z; g[7] += hx * w1.w;
      float2 wc = *(const float2*)(Wc + (size_t)(k0 + i) * 2);
      c0 += hx * wc.x; c1 += hx * wc.y;
    }
  }
  #pragma unroll
  for (int s = 32; s > 0; s >>= 1) {
    #pragma unroll
    for (int e = 0; e < 8; ++e) g[e] += __shfl_down(g[e], s);
    c0 += __shfl_down(c0, s);
    c1 += __shfl_down(c1, s);
  }
  if (lane == 0) {
    float m = g[0];
    #pragma unroll
    for (int e = 1; e < 8; ++e) m = fmaxf(m, g[e]);
    float ex[8], ssum = 0.f;
    #pragma unroll
    for (int e = 0; e < 8; ++e) { ex[e] = expf(g[e] - m); ssum += ex[e]; }
    float inv = 1.f / ssum;
    float ge[8];
    #pragma unroll
    for (int e = 0; e < 8; ++e) ge[e] = ex[e] * inv;
    float v0 = -1.f, v1 = -1.f; int i0 = 0, i1 = 0;
    #pragma unroll
    for (int e = 0; e < 8; ++e) {
      float v = ge[e];
      if (v > v0)      { v1 = v0; i1 = i0; v0 = v; i0 = e; }
      else if (v > v1) { v1 = v; i1 = e; }
    }
    float wsum = v0 + v1 + 1e-9f;
    float w0 = v0 / wsum, w1 = v1 / wsum;
    float ca = c0 + bc[0], cb = c1 + bc[1];
    float mm = fmaxf(ca, cb);
    float e0 = expf(ca - mm), e1 = expf(cb - mm);
    float cinv = 1.f / (e0 + e1);
    int r0 = atomicAdd(&cnt[i0], 1);
    int r1 = atomicAdd(&cnt[i1], 1);
    tokA[t] = make_int4(i0, i1, r0, r1);
    tokB[t] = make_float4(w0, w1, e0 * cinv, e1 * cinv);
    #pragma unroll
    for (int e = 0; e < 8; ++e) atomicAdd(&lme[e], ge[e]);
    atomicAdd(&lce[i0], 1.f);
  }
  __syncthreads();
  if (tid < 8) { atomicAdd(&me[tid], lme[tid]); atomicAdd(&ce[tid], lce[tid]); }
}

// ---------------- scan offsets + l_aux ----------------
__global__ void scan_kernel(const int* __restrict__ cnt, int* __restrict__ off,
                            const float* __restrict__ me, const float* __restrict__ ce,
                            float* __restrict__ laux) {
  if (threadIdx.x == 0) {
    int o = 0;
    for (int e = 0; e < 8; ++e) { off[e] = o; o += cnt[e]; }
    off[8] = o;            // == 8192
    off[9] = o + TT;       // == 12288
    float s = 0.f;
    for (int e = 0; e < 8; ++e) s += me[e] * ce[e];
    laux[0] = s * 8.f / ((float)TT * (float)TT);
  }
}

// ---------------- scatter h rows into permuted layout ----------------
__global__ __launch_bounds__(256) void scatter_kernel(const u16* __restrict__ hbf,
                                                      u16* __restrict__ hperm,
                                                      const int4* __restrict__ tokA,
                                                      const int* __restrict__ off) {
  int t = blockIdx.x, tid = threadIdx.x;
  int4 a = tokA[t];
  size_t p0 = (size_t)(off[a.x] + a.z) * HD;
  size_t p1 = (size_t)(off[a.y] + a.w) * HD;
  size_t pr = (size_t)(8192 + t) * HD;
  uint2 v = ((const uint2*)(hbf + (size_t)t * HD))[tid];
  ((uint2*)(hperm + p0))[tid] = v;
  ((uint2*)(hperm + p1))[tid] = v;
  ((uint2*)(hperm + pr))[tid] = v;
}

// ---------------- combine (sums G3 partials) + classification head ----------------
__global__ __launch_bounds__(256) void combine_head(const float* __restrict__ eoutA,
                                                    const float* __restrict__ eoutB,
                                                    const int4* __restrict__ tokA,
                                                    const float4* __restrict__ tokB,
                                                    const int* __restrict__ off,
                                                    const float* __restrict__ Wh,
                                                    const float* __restrict__ bh,
                                                    float* __restrict__ logits) {
  int tid = threadIdx.x, lane = tid & 63, wid = tid >> 6;
  int t = blockIdx.x * 4 + wid;
  int4 a = tokA[t];
  float4 b = tokB[t];
  size_t r0 = (size_t)(off[a.x] + a.z) * HD;
  size_t r1 = (size_t)(off[a.y] + a.w) * HD;
  size_t rr = (size_t)(8192 + t) * HD;
  float acc[10] = {};
  for (int cc = 0; cc < 4; ++cc) {
    int k0 = cc * 256 + lane * 4;
    float v0a[4], v1a[4], vra[4], v0b[4], v1b[4], vrb[4];
    *(float4*)v0a = *(const float4*)(eoutA + r0 + k0);
    *(float4*)v1a = *(const float4*)(eoutA + r1 + k0);
    *(float4*)vra = *(const float4*)(eoutA + rr + k0);
    *(float4*)v0b = *(const float4*)(eoutB + r0 + k0);
    *(float4*)v1b = *(const float4*)(eoutB + r1 + k0);
    *(float4*)vrb = *(const float4*)(eoutB + rr + k0);
    #pragma unroll
    for (int i = 0; i < 4; ++i) {
      float e0 = v0a[i] + v0b[i];
      float e1 = v1a[i] + v1b[i];
      float er = vra[i] + vrb[i];
      float outv = b.z * (b.x * e0 + b.y * e1) + b.w * er;
      const float* wr = Wh + (size_t)(k0 + i) * 10;
      #pragma unroll
      for (int j = 0; j < 10; ++j) acc[j] += outv * wr[j];
    }
  }
  #pragma unroll
  for (int s = 32; s > 0; s >>= 1) {
    #pragma unroll
    for (int j = 0; j < 10; ++j) acc[j] += __shfl_down(acc[j], s);
  }
  if (lane == 0) {
    #pragma unroll
    for (int j = 0; j < 10; ++j) logits[(size_t)t * 10 + j] = acc[j] + bh[j];
  }
}

// ---------------- launch ----------------
extern "C" void kernel_launch(void* const* d_in, const int* in_sizes, int n_in,
                              void* d_out, int out_size, void* d_ws, size_t ws_size,
                              hipStream_t stream) {
  const float* x   = (const float*)d_in[0];
  const float* Wb  = (const float*)d_in[1];
  const float* bb  = (const float*)d_in[2];
  const float* Wg  = (const float*)d_in[3];
  const float* W1  = (const float*)d_in[4];
  const float* b1  = (const float*)d_in[5];
  const float* W2  = (const float*)d_in[6];
  const float* b2  = (const float*)d_in[7];
  const float* Wr1 = (const float*)d_in[8];
  const float* br1 = (const float*)d_in[9];
  const float* Wr2 = (const float*)d_in[10];
  const float* br2 = (const float*)d_in[11];
  const float* Wc  = (const float*)d_in[12];
  const float* bc  = (const float*)d_in[13];
  const float* Wh  = (const float*)d_in[14];
  const float* bh  = (const float*)d_in[15];
  float* out = (float*)d_out;

  char* w = (char*)d_ws;
  u16*    xcat  = (u16*)(w + OFF_XCAT);
  u16*    wbcat = (u16*)(w + OFF_WBCAT);
  u16*    w1t   = (u16*)(w + OFF_W1T);
  u16*    w2t   = (u16*)(w + OFF_W2T);
  float*  b1s   = (float*)(w + OFF_B1S);
  float*  b2s   = (float*)(w + OFF_B2S);
  float*  h32a  = (float*)(w + OFF_H32);
  u16*    hbf   = (u16*)(w + OFF_HBF);
  u16*    hperm = (u16*)(w + OFF_HPERM);
  u16*    mid   = (u16*)(w + OFF_MID);
  float*  eoutA = (float*)(w + OFF_EOUT);
  int4*   tokA  = (int4*)(w + OFF_TOKA);
  float4* tokB  = (float4*)(w + OFF_TOKB);
  int*    cnt   = (int*)(w + OFF_META);
  int*    off   = cnt + 16;
  float*  me    = (float*)(off + 16);
  float*  ce    = me + 8;
  // lifetime-aliased partial buffers (see layout comment)
  float*  h32b  = (float*)(w + OFF_EOUT);   // dead before G3 writes eoutA
  float*  eoutB = (float*)(w + OFF_XCAT);   // xcat/wbcat/w1t-prefix dead after G2

  // conversions (independent)
  xcat_kernel<<<dim3(2048), dim3(256), 0, stream>>>(x, xcat);
  wbcat_kernel<<<dim3(16, 16), dim3(256), 0, stream>>>(Wb, wbcat);
  transpose_cvt<<<dim3(64, 16, 9), dim3(256), 0, stream>>>(W1, Wr1, w1t, 1024, 4096);
  transpose_cvt<<<dim3(16, 64, 9), dim3(256), 0, stream>>>(W2, Wr2, w2t, 4096, 1024);
  prep_kernel<<<dim3(181), dim3(256), 0, stream>>>(b1, br1, b2, br2, b1s, b2s, cnt, off, me, ce);

  // G1: h_pre = x@Wb + bb, split-bf16 (K=3072), split-K=2 partial stores
  gemm_bt<0, 1, 0, 2><<<dim3(8, 32, 2), dim3(256), 0, stream>>>(
      xcat, wbcat, bb, h32a, h32b, (u16*)nullptr, (const int*)nullptr, 4096, 3072, 1024);
  relu_cast<<<dim3(2048), dim3(256), 0, stream>>>(h32a, h32b, h32a, hbf);

  gating_kernel<<<dim3(1024), dim3(256), 0, stream>>>(h32a, Wg, Wc, bc, tokA, tokB, me, ce, cnt);
  scan_kernel<<<dim3(1), dim3(64), 0, stream>>>(cnt, off, me, ce, out + 40960);
  scatter_kernel<<<dim3(4096), dim3(256), 0, stream>>>(hbf, hperm, tokA, off);

  // G2: mid = relu(hperm @ W1[e] + b1[e]) grouped over 9 "experts" (8 MoE + residual)
  gemm_bt<1, 0, 1, 1><<<dim3(32, 32, 9), dim3(256), 0, stream>>>(
      hperm, w1t, b1s, (float*)nullptr, (float*)nullptr, mid, off, 0, 1024, 4096);
  // G3: eout partials = mid @ W2[e] (+ b2[e] in chunk0), split-K=2
  gemm_bt<0, 1, 0, 2><<<dim3(8, 32, 18), dim3(256), 0, stream>>>(
      mid, w2t, b2s, eoutA, eoutB, (u16*)nullptr, off, 0, 4096, 1024);

  combine_head<<<dim3(1024), dim3(256), 0, stream>>>(eoutA, eoutB, tokA, tokB, off, Wh, bh, out);
}